// Round 6
// baseline (178.979 us; speedup 1.0000x reference)
//
#include <hip/hip_runtime.h>
#include <cstdint>
#include <cstddef>

// DigitCapsules routing: B=256, R=1152, C=10, IC=8, OC=16, 3 iters.
// R23: eliminate u entirely (94 MB store + 2x47 MB read = the two walls).
// Passes recompute u from f16 W staged in LDS, with b AS THE LANE DIM:
//  - W[r][c][oq] reads are wave-uniform -> LDS broadcast (free, m136);
//    kills R18/R21's scattered per-lane W-gather latency wall.
//  - softmax over c is lane-local (all 10 c in regs; only 2 shfl per c
//    for the o-dot); kills R19's cross-thread-softmax DS-pipe wall.
//  - r-sum accumulates IN-THREAD (acc[10][4] over block r-tile); one
//    cross-wave LDS reduce per block (not per b).
// Kernels:
//   L1 u0: u_s1 minus u-store + wf16 emit (bg==0, R18-proven) -> part1.
//   L2 s1red (R15 verbatim): v1 = squash(0.1*sum part1).
//   L3 passB(x,wf16,v1 -> pA [144][256][160] f32)
//   L4 redN(pA, vprev=v1 -> v2)
//   L5 passB(x,wf16,v2 -> pB)
//   L6 redN(pB, null -> out)
// Logits linear in v: b_t = u.(v1+..+v_{t-1}) -> running vsum (proven).
#define NB 256
#define NR 1152
#define NC 10
#define NI 8
#define NO 16
#define NRC 144      // 8-r chunks (u0 rc, passB rc, partout chunks)

typedef _Float16 h2 __attribute__((ext_vector_type(2)));

#if defined(__has_builtin)
#if __has_builtin(__builtin_amdgcn_fdot2)
#define HAS_FDOT2 1
#endif
#if __has_builtin(__builtin_amdgcn_cvt_pkrtz)
#define HAS_PKRTZ 1
#endif
#endif

static __device__ __forceinline__ float fdot2(uint32_t a, uint32_t b, float c) {
#ifdef HAS_FDOT2
    return __builtin_amdgcn_fdot2(__builtin_bit_cast(h2, a),
                                  __builtin_bit_cast(h2, b), c, false);
#else
    const h2 av = __builtin_bit_cast(h2, a);
    const h2 bv = __builtin_bit_cast(h2, b);
    c = fmaf((float)av.x, (float)bv.x, c);
    return fmaf((float)av.y, (float)bv.y, c);
#endif
}

static __device__ __forceinline__ uint32_t pk_f16(float a, float b) {
#ifdef HAS_PKRTZ
    return __builtin_bit_cast(uint32_t, __builtin_amdgcn_cvt_pkrtz(a, b));
#else
    h2 v; v.x = (_Float16)a; v.y = (_Float16)b;
    return __builtin_bit_cast(uint32_t, v);
#endif
}

static __device__ __forceinline__ uint32_t bf16_pack2(float lo, float hi) {
    uint32_t vl = __float_as_uint(lo);
    vl = vl + 0x7FFFu + ((vl >> 16) & 1u);
    uint32_t vh = __float_as_uint(hi);
    vh = vh + 0x7FFFu + ((vh >> 16) & 1u);
    return (vl >> 16) | (vh & 0xFFFF0000u);
}

// -------------------------------------------------------------------------
// u0: 2304 blocks = 144 rc x 16 bg; 320 thr = c*32 + rl*4 + oq.
// = R22's caps_u_s1 with the u-store DELETED (nothing reads u anymore)
// and wf16 emission added (bg==0 blocks, R18-proven layout
// wf16[r][c][oq][od*4+ip] f16x2). Outputs: part1 bf16 (proven format).
__global__ __launch_bounds__(320) void caps_u0_kernel(
    const float* __restrict__ x, const float* __restrict__ W,
    uint32_t* __restrict__ part1, uint32_t* __restrict__ wf16)
{
    const int t  = threadIdx.x;
    const int c  = t >> 5;             // 0..9
    const int rl = (t & 31) >> 2;      // 0..7
    const int oq = t & 3;              // 0..3
    const int rc = blockIdx.x >> 4;    // 0..143
    const int bg = blockIdx.x & 15;    // 0..15
    const int b0 = bg * 16;
    const int r  = rc * 8 + rl;

    __shared__ float xs[16][8][8];     // 4 KB

    if (t < 256) {                     // 256 float4 = x[b0..+16)[rc*8..+8)[8]
        const int bi = t >> 4, rem = t & 15;
        const int rr = rem >> 1, hf = rem & 1;
        *(float4*)&xs[bi][rr][hf * 4] =
            *(const float4*)(x + ((size_t)(b0 + bi) * NR + rc * 8 + rr) * 8 + hf * 4);
    }

    const float* wb = W + ((size_t)r * NC + c) * (NI * NO) + oq * 4;
    float4 wf[8];
#pragma unroll
    for (int i = 0; i < 8; ++i) wf[i] = *(const float4*)(wb + i * NO);

    if (bg == 0) {                     // W f16 conversion, once per element
        const float* wfl = (const float*)wf;   // wfl[i*4+od]
        uint32_t* dst = wf16 + (((size_t)r * NC + c) * 4 + oq) * 16;
#pragma unroll
        for (int od = 0; od < 4; ++od) {
            uint4 wq;
            wq.x = pk_f16(wfl[0 * 4 + od], wfl[1 * 4 + od]);
            wq.y = pk_f16(wfl[2 * 4 + od], wfl[3 * 4 + od]);
            wq.z = pk_f16(wfl[4 * 4 + od], wfl[5 * 4 + od]);
            wq.w = pk_f16(wfl[6 * 4 + od], wfl[7 * 4 + od]);
            *(uint4*)(dst + od * 4) = wq;
        }
    }

    __syncthreads();

#pragma unroll 2
    for (int bi = 0; bi < 16; ++bi) {
        const float4 xv4a = *(const float4*)&xs[bi][rl][0];
        const float4 xv4b = *(const float4*)&xs[bi][rl][4];
        const float xr[8] = {xv4a.x, xv4a.y, xv4a.z, xv4a.w,
                             xv4b.x, xv4b.y, xv4b.z, xv4b.w};
        float ax = 0.f, ay = 0.f, az = 0.f, aw = 0.f;
#pragma unroll
        for (int i = 0; i < 8; ++i) {
            const float xv = xr[i];
            ax = fmaf(xv, wf[i].x, ax); ay = fmaf(xv, wf[i].y, ay);
            az = fmaf(xv, wf[i].z, az); aw = fmaf(xv, wf[i].w, aw);
        }
        // fused s1 partial: reduce fp32 quad over rl (lane bits 2..4)
        float sx = ax, sy = ay, sz = az, sw = aw;
#pragma unroll
        for (int off = 4; off <= 16; off <<= 1) {
            sx += __shfl_xor(sx, off); sy += __shfl_xor(sy, off);
            sz += __shfl_xor(sz, off); sw += __shfl_xor(sw, off);
        }
        if ((t & 28) == 0) {   // rl == 0 lanes: one uint2 per (bi,c,oq)
            uint2 p;
            p.x = bf16_pack2(sx, sy);
            p.y = bf16_pack2(sz, sw);
            *(uint2*)(part1 + ((size_t)(b0 + bi) * NRC + rc) * 80
                      + c * 8 + oq * 2) = p;
        }
    }
}

// -------------------------------------------------------------------------
// s1red: v1 = squash(0.1 * sum over 144 rc of bf16 part1).  (R15 verbatim)
__global__ __launch_bounds__(192) void caps_s1_reduce_kernel(
    const uint32_t* __restrict__ part1, float* __restrict__ vsum)
{
    const int b = blockIdx.x;
    const int t = threadIdx.x;
    if (t >= 160) return;
    const uint32_t* p = part1 + (size_t)b * NRC * 80 + (t >> 1);
    const bool hi = t & 1;
    float s0 = 0.f, s1 = 0.f, s2 = 0.f, s3 = 0.f;
#pragma unroll 4
    for (int g = 0; g < NRC; g += 4) {
        const uint32_t w0 = p[(g + 0) * 80];
        const uint32_t w1 = p[(g + 1) * 80];
        const uint32_t w2 = p[(g + 2) * 80];
        const uint32_t w3 = p[(g + 3) * 80];
        s0 += hi ? __uint_as_float(w0 & 0xFFFF0000u) : __uint_as_float(w0 << 16);
        s1 += hi ? __uint_as_float(w1 & 0xFFFF0000u) : __uint_as_float(w1 << 16);
        s2 += hi ? __uint_as_float(w2 & 0xFFFF0000u) : __uint_as_float(w2 << 16);
        s3 += hi ? __uint_as_float(w3 & 0xFFFF0000u) : __uint_as_float(w3 << 16);
    }
    const float s = 0.1f * ((s0 + s1) + (s2 + s3));
    float n2 = s * s;
    n2 += __shfl_xor(n2, 1);
    n2 += __shfl_xor(n2, 2);
    n2 += __shfl_xor(n2, 4);
    n2 += __shfl_xor(n2, 8);
    const float nrm = sqrtf(n2);
    vsum[(size_t)b * 160 + t] = s * (n2 / (1.f + n2) / (nrm + 1e-8f));
}

// -------------------------------------------------------------------------
// passB (R23): 2304 blocks = 144 rc x 16 bg; 256 thr = 4 waves.
// Lane = (bl 0..15, oq 0..3); wave wv owns r_local {wv*2, wv*2+1}.
// LDS: W tile [8r][10c][4oq][16]u32 (20480 B, broadcast reads) +
// x f16 [8r][16b][4]u32 (2048 B) + vt f32 [10c][4oq][16b][4] (10240 B);
// sred [4wv][10][4][16][4] f32 (40960 B) ALIASED over W+x after barrier.
// Per r: 10c x (16 fdot2 from broadcast W + logit partial + 2 shfl);
// lane-local softmax; acc[10][4] in-thread over both r.
// Epilogue: cross-wave LDS reduce -> partout[rc][b][160] f32.
__global__ __launch_bounds__(256) void caps_passB_kernel(
    const float* __restrict__ x, const uint32_t* __restrict__ wf16,
    const float* __restrict__ vsum, float* __restrict__ partout)
{
    const int t    = threadIdx.x;
    const int rc   = blockIdx.x >> 4;   // 0..143
    const int bg   = blockIdx.x & 15;   // 0..15
    const int b0   = bg * 16;
    const int r0   = rc * 8;
    const int lane = t & 63;
    const int bl   = lane & 15;         // b-lane
    const int oq   = lane >> 4;         // 0..3
    const int wv   = t >> 6;            // wave 0..3

    __shared__ __align__(16) uint8_t smraw[40960];  // union: (W+x) | sred
    __shared__ __align__(16) float vt[10][4][16][4];

    uint32_t (*wld)[10][4][16] = (uint32_t(*)[10][4][16])smraw;       // [8r]
    uint32_t (*xld)[16][4]     = (uint32_t(*)[16][4])(smraw + 20480); // [8r]
    float (*sred)[10][4][16][4] = (float(*)[10][4][16][4])smraw;      // [4wv]

    // stage W: 20480 B = 1280 uint4; 5 per thread, coalesced
    {
        const uint4* src = (const uint4*)(wf16 + (size_t)r0 * 640);
        uint4* dst = (uint4*)smraw;
#pragma unroll
        for (int i = 0; i < 5; ++i) dst[i * 256 + t] = src[i * 256 + t];
    }
    // stage x -> f16: 256 float4, 1 per thread; t = bs*16 + rs*2 + hf
    {
        const int bs = t >> 4, rs = (t >> 1) & 7, hf = t & 1;
        const float4 xv4 =
            *(const float4*)(x + ((size_t)(b0 + bs) * NR + r0 + rs) * 8 + hf * 4);
        uint2 xp;
        xp.x = pk_f16(xv4.x, xv4.y);
        xp.y = pk_f16(xv4.z, xv4.w);
        *(uint2*)&xld[rs][bs][hf * 2] = xp;
    }
    // stage vt transposed: vt[c][oq][b][j] = v[b0+b][c*16+oq*4+j]
    {
        const int bs = t >> 4, rem = t & 15;
        const int oqr = rem >> 2, j = rem & 3;
#pragma unroll
        for (int it = 0; it < 10; ++it)
            vt[it][oqr][bs][j] = vsum[(size_t)(b0 + bs) * 160 + it * 16 + rem];
    }
    __syncthreads();

    float acc[10][4];
#pragma unroll
    for (int c = 0; c < 10; ++c)
#pragma unroll
        for (int j = 0; j < 4; ++j) acc[c][j] = 0.f;

#pragma unroll
    for (int ri = 0; ri < 2; ++ri) {
        const int rl = wv * 2 + ri;
        const uint4 xv = *(const uint4*)&xld[rl][bl][0];
        float us[10][4], lg[10];
#pragma unroll
        for (int c = 0; c < 10; ++c) {
            const uint4* wp = (const uint4*)&wld[rl][c][oq][0];
            const uint4 w0 = wp[0], w1 = wp[1], w2 = wp[2], w3 = wp[3];
            float u0 = fdot2(xv.x, w0.x, 0.f);
            u0 = fdot2(xv.y, w0.y, u0);
            u0 = fdot2(xv.z, w0.z, u0);
            u0 = fdot2(xv.w, w0.w, u0);
            float u1 = fdot2(xv.x, w1.x, 0.f);
            u1 = fdot2(xv.y, w1.y, u1);
            u1 = fdot2(xv.z, w1.z, u1);
            u1 = fdot2(xv.w, w1.w, u1);
            float u2 = fdot2(xv.x, w2.x, 0.f);
            u2 = fdot2(xv.y, w2.y, u2);
            u2 = fdot2(xv.z, w2.z, u2);
            u2 = fdot2(xv.w, w2.w, u2);
            float u3 = fdot2(xv.x, w3.x, 0.f);
            u3 = fdot2(xv.y, w3.y, u3);
            u3 = fdot2(xv.z, w3.z, u3);
            u3 = fdot2(xv.w, w3.w, u3);
            us[c][0] = u0; us[c][1] = u1; us[c][2] = u2; us[c][3] = u3;
            const float4 vq = *(const float4*)&vt[c][oq][bl][0];
            float d = u0 * vq.x;
            d = fmaf(u1, vq.y, d);
            d = fmaf(u2, vq.z, d);
            d = fmaf(u3, vq.w, d);
            lg[c] = d;
        }
#pragma unroll
        for (int c = 0; c < 10; ++c) {    // finish o-dot across oq lanes
            lg[c] += __shfl_xor(lg[c], 16);
            lg[c] += __shfl_xor(lg[c], 32);
        }
        float m = lg[0];
#pragma unroll
        for (int c = 1; c < 10; ++c) m = fmaxf(m, lg[c]);
        float wgt[10], ssum = 0.f;
#pragma unroll
        for (int c = 0; c < 10; ++c) { wgt[c] = __expf(lg[c] - m); ssum += wgt[c]; }
        const float inv = 1.f / ssum;
#pragma unroll
        for (int c = 0; c < 10; ++c) {
            const float wx = wgt[c] * inv;
            acc[c][0] = fmaf(wx, us[c][0], acc[c][0]);
            acc[c][1] = fmaf(wx, us[c][1], acc[c][1]);
            acc[c][2] = fmaf(wx, us[c][2], acc[c][2]);
            acc[c][3] = fmaf(wx, us[c][3], acc[c][3]);
        }
    }

    __syncthreads();   // all waves done reading W/x before sred aliases them
#pragma unroll
    for (int c = 0; c < 10; ++c) {
        float4 tmp;
        tmp.x = acc[c][0]; tmp.y = acc[c][1];
        tmp.z = acc[c][2]; tmp.w = acc[c][3];
        *(float4*)&sred[wv][c][oq][bl][0] = tmp;
    }
    __syncthreads();
    {
        const int bs = t >> 4, rem = t & 15;
        const int oqr = rem >> 2, j = rem & 3;
#pragma unroll
        for (int it = 0; it < 10; ++it) {
            const float s = sred[0][it][oqr][bs][j] + sred[1][it][oqr][bs][j]
                          + sred[2][it][oqr][bs][j] + sred[3][it][oqr][bs][j];
            partout[((size_t)rc * NB + b0 + bs) * 160 + it * 16 + rem] = s;
        }
    }
}

// -------------------------------------------------------------------------
// redN: outv = (vprev? vprev : 0) + squash(sum over 144 rc of f32 part).
// grid 256 (b), 192 thr (160 active). Final call writes d_out directly.
__global__ __launch_bounds__(192) void caps_redN_kernel(
    const float* __restrict__ part, const float* __restrict__ vprev,
    float* __restrict__ outv)
{
    const int b = blockIdx.x;
    const int t = threadIdx.x;
    if (t >= 160) return;
    float s = 0.f;
#pragma unroll 4
    for (int g = 0; g < NRC; ++g)
        s += part[((size_t)g * NB + b) * 160 + t];
    float n2 = s * s;
    n2 += __shfl_xor(n2, 1);
    n2 += __shfl_xor(n2, 2);
    n2 += __shfl_xor(n2, 4);
    n2 += __shfl_xor(n2, 8);
    const float nrm = sqrtf(n2);
    float v = s * (n2 / (1.f + n2) / (nrm + 1e-8f));
    if (vprev != nullptr) v += vprev[(size_t)b * 160 + t];
    outv[(size_t)b * 160 + t] = v;
}

// -------------------------------------------------------------------------
extern "C" void kernel_launch(void* const* d_in, const int* in_sizes, int n_in,
                              void* d_out, int out_size, void* d_ws, size_t ws_size,
                              hipStream_t stream) {
    const float* x = (const float*)d_in[0];   // [256,1152,8]
    const float* W = (const float*)d_in[1];   // [1,1152,10,8,16]
    float* out = (float*)d_out;               // [256,10,16] = [256][160]

    // ws: part1 [256][144][80]u32 = 11,796,480
    //     wf16  [1152][10][4][16] =  2,949,120
    //     pA [144][256][160]f32   = 23,592,960
    //     pB [144][256][160]f32   = 23,592,960
    //     v1 163,840 | v2 163,840           (total 62,259,200 B)
    uint8_t*  ws   = (uint8_t*)d_ws;
    uint32_t* prt1 = (uint32_t*)ws;
    uint32_t* wf16 = (uint32_t*)(ws + 11796480u);
    float*    pA   = (float*)(ws + 14745600u);
    float*    pB   = (float*)(ws + 38338560u);
    float*    v1   = (float*)(ws + 61931520u);
    float*    v2   = (float*)(ws + 62095360u);

    caps_u0_kernel       <<<2304, 320, 0, stream>>>(x, W, prt1, wf16);
    caps_s1_reduce_kernel<<<NB, 192, 0, stream>>>(prt1, v1);
    caps_passB_kernel    <<<2304, 256, 0, stream>>>(x, wf16, v1, pA);
    caps_redN_kernel     <<<NB, 192, 0, stream>>>(pA, v1, v2);
    caps_passB_kernel    <<<2304, 256, 0, stream>>>(x, wf16, v2, pB);
    caps_redN_kernel     <<<NB, 192, 0, stream>>>(pB, nullptr, out);
}